// Round 6
// baseline (68.835 us; speedup 1.0000x reference)
//
#include <hip/hip_runtime.h>
#include <math.h>

#define N 8192
#define D 1024

typedef float f32x4 __attribute__((ext_vector_type(4)));

// K1: per-row dot products. One wave (64 lanes) per row; 4 rows per 256-thr block.
__global__ __launch_bounds__(256) void dot_rows(const float* __restrict__ q,
                                                const float* __restrict__ k,
                                                float* __restrict__ raw) {
    const int wave = threadIdx.x >> 6;
    const int lane = threadIdx.x & 63;
    const int row  = blockIdx.x * 4 + wave;
    const float4* q4 = (const float4*)(q + (size_t)row * D);
    const float4* k4 = (const float4*)(k + (size_t)row * D);
    float s = 0.f;
    #pragma unroll
    for (int i = 0; i < 4; ++i) {             // D/4 = 256 float4s, 64 lanes -> 4 each
        float4 a = q4[lane + 64 * i];
        float4 b = k4[lane + 64 * i];
        s += a.x * b.x + a.y * b.y + a.z * b.z + a.w * b.w;
    }
    #pragma unroll
    for (int off = 32; off; off >>= 1) s += __shfl_down(s, off, 64);
    if (lane == 0) raw[row] = s;
}

// K2: block 0 = softmax over raw[8192] + scatter diag values.
//     blocks 1..2048 = zero-fill 4 rows each with PLAIN (cached) stores,
//     skipping the one diagonal word per row (block 0 owns those addresses).
//     Cached stores let the 256 MiB output stay L3-resident across graph
//     replays (write-elision); NT stores forced every byte to HBM.
__global__ __launch_bounds__(256) void fill_and_softmax(const float* __restrict__ raw,
                                                        float* __restrict__ out) {
    const int bid = blockIdx.x;
    const int t   = threadIdx.x;

    if (bid == 0) {
        // ---- softmax + diagonal scatter (256 threads, 32 rows each) ----
        const int lane = t & 63;
        const int wid  = t >> 6;              // 4 waves
        __shared__ float red[4];

        // pass 1: max
        float m = -INFINITY;
        #pragma unroll
        for (int i = 0; i < 32; ++i) m = fmaxf(m, raw[t + 256 * i]);
        #pragma unroll
        for (int off = 32; off; off >>= 1) m = fmaxf(m, __shfl_down(m, off, 64));
        if (lane == 0) red[wid] = m;
        __syncthreads();
        m = fmaxf(fmaxf(red[0], red[1]), fmaxf(red[2], red[3]));
        __syncthreads();

        // pass 2: sum of exp
        float s = 0.f;
        #pragma unroll
        for (int i = 0; i < 32; ++i) s += __expf(raw[t + 256 * i] - m);
        #pragma unroll
        for (int off = 32; off; off >>= 1) s += __shfl_down(s, off, 64);
        if (lane == 0) red[wid] = s;
        __syncthreads();
        const float inv = 1.0f / (red[0] + red[1] + red[2] + red[3]);

        // pass 3: write diagonal entries
        #pragma unroll
        for (int i = 0; i < 32; ++i) {
            const int r = t + 256 * i;
            out[(size_t)r * (N + 1)] = __expf(raw[r] - m) * inv;
        }
    } else {
        // ---- fill role: rows 4*fb .. 4*fb+3, 8192 float4s per block ----
        const int fb = bid - 1;               // 0..2047
        f32x4* o4 = (f32x4*)out + (size_t)fb * 8192;
        const f32x4 z = {0.f, 0.f, 0.f, 0.f};
        #pragma unroll
        for (int i = 0; i < 32; ++i) {
            const int g = t + 256 * i;        // within-slice float4 index
            if ((g & 2047) == fb) {
                // this float4 contains the diagonal of row 4*fb + (g>>11);
                // write the 3 non-diagonal words only
                const int j = g >> 11;        // word to skip
                float* w = (float*)(o4 + g);
                #pragma unroll
                for (int c = 0; c < 4; ++c)
                    if (c != j) w[c] = 0.f;
            } else {
                o4[g] = z;
            }
        }
    }
}

extern "C" void kernel_launch(void* const* d_in, const int* in_sizes, int n_in,
                              void* d_out, int out_size, void* d_ws, size_t ws_size,
                              hipStream_t stream) {
    const float* q = (const float*)d_in[0];
    const float* k = (const float*)d_in[1];
    float* out = (float*)d_out;
    float* raw = (float*)d_ws;                 // 8192 floats

    dot_rows<<<N / 4, 256, 0, stream>>>(q, k, raw);
    fill_and_softmax<<<N / 4 + 1, 256, 0, stream>>>(raw, out);
}